// Round 5
// baseline (304.780 us; speedup 1.0000x reference)
//
#include <hip/hip_runtime.h>
#include <hip/hip_cooperative_groups.h>
#include <math.h>

namespace cg = cooperative_groups;

#define DD 512

// ---------- workspace layout (float offsets) ----------
// 0     : p[8][4][512]     qk partials: [chunk c][head h][col e], raw
// 16384 : sm_c[16][4]      16 contention copies of softmax denom per head
// 16448 : w2_c[16][4]      16 copies of weighted-rm sums
// 16512 : c_raw[16][2048]  16 contention copies of weighted-x context (atomics)
// 49280 : o[512]           attention output
// 49792 : y[512]           residual row
// 50304 : h1[512]          MLP hidden

__device__ __forceinline__ float dot4(float4 a, float4 b) {
    return a.x * b.x + a.y * b.y + a.z * b.z + a.w * b.w;
}
__device__ __forceinline__ float wred(float v) {
#pragma unroll
    for (int m = 32; m; m >>= 1) v += __shfl_xor(v, m, 64);
    return v;
}
__device__ __forceinline__ float4 f4fma(float4 acc, float s, float4 v) {
    acc.x += s * v.x; acc.y += s * v.y; acc.z += s * v.z; acc.w += s * v.w;
    return acc;
}
__device__ __forceinline__ float4 f4add(float4 a, float4 b) {
    a.x += b.x; a.y += b.y; a.z += b.z; a.w += b.w; return a;
}
__device__ __forceinline__ float4 f4muls(float4 a, float4 g, float s) {
    a.x *= g.x * s; a.y *= g.y * s; a.z *= g.z * s; a.w *= g.w * s; return a;
}
__device__ __forceinline__ float hsum4(float4 a) { return a.x + a.y + a.z + a.w; }
__device__ __forceinline__ float4 lnrm4(float4 v, float m, float r, float4 g, float4 b) {
    float4 o;
    o.x = (v.x - m) * r * g.x + b.x; o.y = (v.y - m) * r * g.y + b.y;
    o.z = (v.z - m) * r * g.z + b.z; o.w = (v.w - m) * r * g.w + b.w;
    return o;
}
__device__ __forceinline__ float4 caff4(float4 c, float inv, float w2t, float4 g, float4 b) {
    float4 o;
    o.x = g.x * (c.x * inv - w2t) + b.x; o.y = g.y * (c.y * inv - w2t) + b.y;
    o.z = g.z * (c.z * inv - w2t) + b.z; o.w = g.w * (c.w * inv - w2t) + b.w;
    return o;
}

// ---------- kA: fused q + qk chunk partials (32 blocks: h = bi>>3, c = bi&7) ----------
// block bi: LN(x0); q[h*128 + c*16 .. +15]; p[c][h][e] = sum_{d in chunk} q_d * Wk[.,e]
// Also zero-inits the atomic accumulation buffers (ws poisoned 0xAA each call).
__global__ __launch_bounds__(512) void kA(const float* __restrict__ x,
                                          const float* __restrict__ w_in,
                                          const float* __restrict__ b_in,
                                          const float* __restrict__ g1,
                                          const float* __restrict__ be1,
                                          float* __restrict__ ws) {
    __shared__ float qh[16];
    int bi = blockIdx.x, tid = threadIdx.x, lane = tid & 63, w = tid >> 6;
    int h = bi >> 3, c = bi & 7;
    // zero-init: c_raw (32 blocks x 1024 floats = 32768) + stats
    ws[16512 + bi * 1024 + tid] = 0.f;
    ws[16512 + bi * 1024 + 512 + tid] = 0.f;
    if (bi == 0 && tid < 128) ws[16384 + tid] = 0.f;
    // LN(x0): every wave computes redundantly (2 KB read, L2-shared)
    const float4* x4 = (const float4*)x;
    float4 a = x4[lane], b = x4[64 + lane];
    float ps = wred(hsum4(a) + hsum4(b));
    float pss = wred(dot4(a, a) + dot4(b, b));
    float m = ps * (1.f / 512.f);
    float r = rsqrtf(pss * (1.f / 512.f) - m * m + 1e-5f);
    const float4* g4 = (const float4*)g1;
    const float4* bb4 = (const float4*)be1;
    float4 xna = lnrm4(a, m, r, g4[lane], bb4[lane]);
    float4 xnb = lnrm4(b, m, r, g4[64 + lane], bb4[64 + lane]);
    // q chunk: wave w computes rows j0 + w*2, j0 + w*2 + 1
    int j0 = h * 128 + c * 16;
    const float4* wr = (const float4*)(w_in + (size_t)(j0 + w * 2) * DD);
    for (int i = 0; i < 2; ++i) {
        float acc = wred(dot4(wr[i * 128 + lane], xna) + dot4(wr[i * 128 + 64 + lane], xnb));
        if (lane == 0) qh[w * 2 + i] = acc + b_in[j0 + w * 2 + i];
    }
    __syncthreads();
    // chunk partial over e = tid (coalesced across tid)
    const float* wk = w_in + (size_t)(DD + j0) * DD + tid;
    float acc = 0.f;
#pragma unroll
    for (int d = 0; d < 16; ++d) acc += qh[d] * wk[(size_t)d * DD];
    ws[c * 2048 + h * 512 + tid] = acc;
}

// ---------- kB: streaming pass over x; shift-free softmax; atomic context tail ----------
// 512 blocks x 512 threads, 16 rows/wave  (hot loop identical to round-2 proven version)
__global__ __launch_bounds__(512) void kB(const float* __restrict__ x,
                                          const float* __restrict__ g1,
                                          float* __restrict__ ws) {
    __shared__ float lds[16384];  // 64 KB
    int tid = threadIdx.x, lane = tid & 63, w = tid >> 6;
    const float4* p4 = (const float4*)ws;
    const float4* g4 = (const float4*)g1;
    const float scale = 0.088388347648318447f;  // 1/sqrt(128)
    float4 ga = g4[lane], gb = g4[64 + lane];
    float4 qa[4], qb[4];
    float qs[4];
#pragma unroll
    for (int h = 0; h < 4; ++h) {
        float4 sa = make_float4(0.f, 0.f, 0.f, 0.f), sb = sa;
#pragma unroll
        for (int c = 0; c < 8; ++c) {
            sa = f4add(sa, p4[c * 512 + h * 128 + lane]);
            sb = f4add(sb, p4[c * 512 + h * 128 + 64 + lane]);
        }
        qa[h] = f4muls(sa, ga, scale);
        qb[h] = f4muls(sb, gb, scale);
        qs[h] = wred(hsum4(qa[h]) + hsum4(qb[h]));
    }
    float sm[4], w2a[4];
    float4 Wa[4], Wb[4];
#pragma unroll
    for (int h = 0; h < 4; ++h) {
        sm[h] = 0.f; w2a[h] = 0.f;
        Wa[h] = make_float4(0.f, 0.f, 0.f, 0.f);
        Wb[h] = make_float4(0.f, 0.f, 0.f, 0.f);
    }
    size_t row0 = ((size_t)blockIdx.x * 8 + w) * 16;
    const float4* xb = (const float4*)x + row0 * 128;
    float4 nxa = xb[lane], nxc = xb[64 + lane];
    for (int r = 0; r < 16; ++r) {
        float4 xa = nxa, xc = nxc;
        if (r < 15) { nxa = xb[(r + 1) * 128 + lane]; nxc = xb[(r + 1) * 128 + 64 + lane]; }
        float ps = hsum4(xa) + hsum4(xc);
        float pss = dot4(xa, xa) + dot4(xc, xc);
        float p0 = dot4(xa, qa[0]) + dot4(xc, qb[0]);
        float p1 = dot4(xa, qa[1]) + dot4(xc, qb[1]);
        float p2 = dot4(xa, qa[2]) + dot4(xc, qb[2]);
        float p3 = dot4(xa, qa[3]) + dot4(xc, qb[3]);
        ps = wred(ps); pss = wred(pss);
        p0 = wred(p0); p1 = wred(p1); p2 = wred(p2); p3 = wred(p3);
        float m = ps * (1.f / 512.f);
        float rr = rsqrtf(pss * (1.f / 512.f) - m * m + 1e-5f);
        float rm = rr * m;
        float pd[4] = {p0, p1, p2, p3};
#pragma unroll
        for (int h = 0; h < 4; ++h) {
            float s = rr * pd[h] - rm * qs[h];   // O(1) scores: exp safe without shift
            float p = __expf(s);
            sm[h] += p;
            w2a[h] += p * rm;
            float pr = p * rr;
            Wa[h] = f4fma(Wa[h], pr, xa);
            Wb[h] = f4fma(Wb[h], pr, xc);
        }
    }
    // ---- per-block stats combine (pure sums) + atomics into 16 contention copies ----
    int copy = blockIdx.x & 15;
    if (lane == 0) {
#pragma unroll
        for (int h = 0; h < 4; ++h) {
            lds[w * 4 + h] = sm[h];
            lds[32 + w * 4 + h] = w2a[h];
        }
    }
    __syncthreads();
    if (tid < 8) {
        int h = tid & 3;
        float a = 0.f;
        if (tid < 4) {
            for (int ww = 0; ww < 8; ++ww) a += lds[ww * 4 + h];
            atomicAdd(&ws[16384 + copy * 4 + h], a);
        } else {
            for (int ww = 0; ww < 8; ++ww) a += lds[32 + ww * 4 + h];
            atomicAdd(&ws[16448 + copy * 4 + h], a);
        }
    }
    __syncthreads();  // stats region consumed; reuse lds front for context reduce
    float4* lw4 = (float4*)(lds + w * 2048);
#pragma unroll
    for (int h = 0; h < 4; ++h) {
        lw4[h * 128 + lane] = Wa[h];
        lw4[h * 128 + 64 + lane] = Wb[h];
    }
    __syncthreads();
    float* cdst = ws + 16512 + (size_t)copy * 2048;
    for (int i = tid; i < 2048; i += 512) {
        float a = lds[i] + lds[2048 + i] + lds[4096 + i] + lds[6144 + i] +
                  lds[8192 + i] + lds[10240 + i] + lds[12288 + i] + lds[14336 + i];
        atomicAdd(cdst + i, a);
    }
}

// ---------- kD: cooperative fused epilogue (128 blocks x 256 threads) ----------
// Phase 1: o = Wv.c + bv   Phase 2: y = x0 + w_out.o + b_out
// Phase 3: h1 = relu(w1.LN(y) + b1)   Phase 4: out = y + w2.h1 + b2
// Live state across grid.sync() is ~zero per thread (everything reloaded from ws).
__global__ __launch_bounds__(256) void kD(const float* __restrict__ x,
                                          const float* __restrict__ w_in,
                                          const float* __restrict__ b_in,
                                          const float* __restrict__ w_out,
                                          const float* __restrict__ b_out,
                                          const float* __restrict__ w1,
                                          const float* __restrict__ b1,
                                          const float* __restrict__ w2,
                                          const float* __restrict__ b2,
                                          const float* __restrict__ g1,
                                          const float* __restrict__ be1,
                                          const float* __restrict__ g2,
                                          const float* __restrict__ be2,
                                          float* __restrict__ ws,
                                          float* __restrict__ out) {
    cg::grid_group grid = cg::this_grid();
    int tid = threadIdx.x, lane = tid & 63, w = tid >> 6;
    int j = blockIdx.x * 4 + w;

    // ---- Phase 1: o[j] = Wv[j] . c(h) + bv[j]; reduce 16 contention copies ----
    {
        int h = j >> 7;  // uniform per block
        float smg = 0.f, w2g = 0.f;
#pragma unroll
        for (int c = 0; c < 16; ++c) {
            smg += ws[16384 + c * 4 + h];
            w2g += ws[16448 + c * 4 + h];
        }
        float inv = 1.f / smg, w2t = w2g * inv;
        float4 cra = make_float4(0.f, 0.f, 0.f, 0.f), crb = cra;
#pragma unroll
        for (int c = 0; c < 16; ++c) {
            const float4* cr = (const float4*)(ws + 16512 + c * 2048 + h * 512);
            cra = f4add(cra, cr[lane]);
            crb = f4add(crb, cr[64 + lane]);
        }
        const float4* g14 = (const float4*)g1;
        const float4* be14 = (const float4*)be1;
        float4 ca = caff4(cra, inv, w2t, g14[lane], be14[lane]);
        float4 cb = caff4(crb, inv, w2t, g14[64 + lane], be14[64 + lane]);
        const float4* wr = (const float4*)(w_in + (size_t)(2 * DD + j) * DD);
        float acc = wred(dot4(wr[lane], ca) + dot4(wr[64 + lane], cb));
        if (lane == 0) ws[49280 + j] = acc + b_in[2 * DD + j];
    }
    grid.sync();

    // ---- Phase 2: y[j] = x0[j] + w_out[j].o + b_out[j] ----
    {
        const float4* wr = (const float4*)(w_out + (size_t)j * DD);
        const float4* o4 = (const float4*)(ws + 49280);
        float acc = wred(dot4(wr[lane], o4[lane]) + dot4(wr[64 + lane], o4[64 + lane]));
        if (lane == 0) ws[49792 + j] = x[j] + acc + b_out[j];
    }
    grid.sync();

    // ---- Phase 3: h1[j] = relu(w1[j].LN(y) + b1[j]) ----
    {
        const float4* y4 = (const float4*)(ws + 49792);
        float4 ya = y4[lane], yb = y4[64 + lane];
        float ps = wred(hsum4(ya) + hsum4(yb));
        float pss = wred(dot4(ya, ya) + dot4(yb, yb));
        float m2 = ps * (1.f / 512.f);
        float r2 = rsqrtf(pss * (1.f / 512.f) - m2 * m2 + 1e-5f);
        const float4* g4 = (const float4*)g2;
        const float4* b4 = (const float4*)be2;
        float4 yna = lnrm4(ya, m2, r2, g4[lane], b4[lane]);
        float4 ynb = lnrm4(yb, m2, r2, g4[64 + lane], b4[64 + lane]);
        const float4* wr = (const float4*)(w1 + (size_t)j * DD);
        float acc = wred(dot4(wr[lane], yna) + dot4(wr[64 + lane], ynb));
        if (lane == 0) ws[50304 + j] = fmaxf(acc + b1[j], 0.f);
    }
    grid.sync();

    // ---- Phase 4: out[j] = y[j] + w2[j].h1 + b2[j] ----
    {
        const float4* h4 = (const float4*)(ws + 50304);
        const float4* wr = (const float4*)(w2 + (size_t)j * DD);
        float acc = wred(dot4(wr[lane], h4[lane]) + dot4(wr[64 + lane], h4[64 + lane]));
        if (lane == 0) out[j] = ws[49792 + j] + acc + b2[j];
    }
}

extern "C" void kernel_launch(void* const* d_in, const int* in_sizes, int n_in,
                              void* d_out, int out_size, void* d_ws, size_t ws_size,
                              hipStream_t stream) {
    (void)in_sizes; (void)n_in; (void)out_size; (void)ws_size;
    const float* x = (const float*)d_in[0];
    const float* w_in = (const float*)d_in[1];
    const float* b_in = (const float*)d_in[2];
    const float* w_out = (const float*)d_in[3];
    const float* b_out = (const float*)d_in[4];
    const float* w1 = (const float*)d_in[5];
    const float* b1 = (const float*)d_in[6];
    const float* w2 = (const float*)d_in[7];
    const float* b2 = (const float*)d_in[8];
    const float* g1 = (const float*)d_in[9];
    const float* be1 = (const float*)d_in[10];
    const float* g2 = (const float*)d_in[11];
    const float* be2 = (const float*)d_in[12];
    float* ws = (float*)d_ws;
    float* out = (float*)d_out;

    hipLaunchKernelGGL(kA, dim3(32), dim3(512), 0, stream, x, w_in, b_in, g1, be1, ws);
    hipLaunchKernelGGL(kB, dim3(512), dim3(512), 0, stream, x, g1, ws);

    void* args[] = {
        (void*)&x, (void*)&w_in, (void*)&b_in, (void*)&w_out, (void*)&b_out,
        (void*)&w1, (void*)&b1, (void*)&w2, (void*)&b2,
        (void*)&g1, (void*)&be1, (void*)&g2, (void*)&be2,
        (void*)&ws, (void*)&out
    };
    hipLaunchCooperativeKernel((const void*)kD, dim3(128), dim3(256), args, 0, stream);
}

// Round 6
// 265.517 us; speedup vs baseline: 1.1479x; 1.1479x over previous
//
#include <hip/hip_runtime.h>
#include <math.h>

#define DD 512

// ---------- workspace layout (float offsets) ----------
// 0     : p[8][4][512]     qk partials: [chunk c][head h][col e], raw
// 16384 : sm_c[16][4]      16 contention copies of softmax denom per head
// 16448 : w2_c[16][4]      16 copies of weighted-rm sums
// 16512 : c_raw[16][2048]  16 contention copies of weighted-x context (atomics)
// 49280 : o[512]           attention output
// 49792 : y[512]           residual row
// 50304 : h1[512]          MLP hidden
// 50816 : bar[4]           grid-barrier counters for kD (ints, zeroed by kA)

__device__ __forceinline__ float dot4(float4 a, float4 b) {
    return a.x * b.x + a.y * b.y + a.z * b.z + a.w * b.w;
}
__device__ __forceinline__ float wred(float v) {
#pragma unroll
    for (int m = 32; m; m >>= 1) v += __shfl_xor(v, m, 64);
    return v;
}
__device__ __forceinline__ float4 f4fma(float4 acc, float s, float4 v) {
    acc.x += s * v.x; acc.y += s * v.y; acc.z += s * v.z; acc.w += s * v.w;
    return acc;
}
__device__ __forceinline__ float4 f4add(float4 a, float4 b) {
    a.x += b.x; a.y += b.y; a.z += b.z; a.w += b.w; return a;
}
__device__ __forceinline__ float4 f4muls(float4 a, float4 g, float s) {
    a.x *= g.x * s; a.y *= g.y * s; a.z *= g.z * s; a.w *= g.w * s; return a;
}
__device__ __forceinline__ float hsum4(float4 a) { return a.x + a.y + a.z + a.w; }
__device__ __forceinline__ float4 lnrm4(float4 v, float m, float r, float4 g, float4 b) {
    float4 o;
    o.x = (v.x - m) * r * g.x + b.x; o.y = (v.y - m) * r * g.y + b.y;
    o.z = (v.z - m) * r * g.z + b.z; o.w = (v.w - m) * r * g.w + b.w;
    return o;
}
__device__ __forceinline__ float4 caff4(float4 c, float inv, float w2t, float4 g, float4 b) {
    float4 o;
    o.x = g.x * (c.x * inv - w2t) + b.x; o.y = g.y * (c.y * inv - w2t) + b.y;
    o.z = g.z * (c.z * inv - w2t) + b.z; o.w = g.w * (c.w * inv - w2t) + b.w;
    return o;
}

// Non-cooperative grid barrier: all nb blocks must be co-resident (nb <= 256,
// zero LDS, low VGPR => guaranteed). Thread 0 releases its block's prior
// writes, arrives, and acquire-spins; __syncthreads() fans visibility out.
__device__ __forceinline__ void gbar(int* cnt, int nb) {
    __syncthreads();
    if (threadIdx.x == 0) {
        __threadfence();
        __hip_atomic_fetch_add(cnt, 1, __ATOMIC_RELEASE, __HIP_MEMORY_SCOPE_AGENT);
        while (__hip_atomic_load(cnt, __ATOMIC_ACQUIRE, __HIP_MEMORY_SCOPE_AGENT) < nb) {}
        __threadfence();
    }
    __syncthreads();
}

// ---------- kA: fused q + qk chunk partials (32 blocks: h = bi>>3, c = bi&7) ----------
__global__ __launch_bounds__(512) void kA(const float* __restrict__ x,
                                          const float* __restrict__ w_in,
                                          const float* __restrict__ b_in,
                                          const float* __restrict__ g1,
                                          const float* __restrict__ be1,
                                          float* __restrict__ ws) {
    __shared__ float qh[16];
    int bi = blockIdx.x, tid = threadIdx.x, lane = tid & 63, w = tid >> 6;
    int h = bi >> 3, c = bi & 7;
    // zero-init: c_raw (32 blocks x 1024 floats) + stats + barrier counters
    ws[16512 + bi * 1024 + tid] = 0.f;
    ws[16512 + bi * 1024 + 512 + tid] = 0.f;
    if (bi == 0 && tid < 128) ws[16384 + tid] = 0.f;
    if (bi == 1 && tid < 4) ws[50816 + tid] = 0.f;   // int 0 == float 0.0 bits
    // LN(x0): every wave computes redundantly (2 KB read, L2-shared)
    const float4* x4 = (const float4*)x;
    float4 a = x4[lane], b = x4[64 + lane];
    float ps = wred(hsum4(a) + hsum4(b));
    float pss = wred(dot4(a, a) + dot4(b, b));
    float m = ps * (1.f / 512.f);
    float r = rsqrtf(pss * (1.f / 512.f) - m * m + 1e-5f);
    const float4* g4 = (const float4*)g1;
    const float4* bb4 = (const float4*)be1;
    float4 xna = lnrm4(a, m, r, g4[lane], bb4[lane]);
    float4 xnb = lnrm4(b, m, r, g4[64 + lane], bb4[64 + lane]);
    int j0 = h * 128 + c * 16;
    const float4* wr = (const float4*)(w_in + (size_t)(j0 + w * 2) * DD);
    for (int i = 0; i < 2; ++i) {
        float acc = wred(dot4(wr[i * 128 + lane], xna) + dot4(wr[i * 128 + 64 + lane], xnb));
        if (lane == 0) qh[w * 2 + i] = acc + b_in[j0 + w * 2 + i];
    }
    __syncthreads();
    const float* wk = w_in + (size_t)(DD + j0) * DD + tid;
    float acc = 0.f;
#pragma unroll
    for (int d = 0; d < 16; ++d) acc += qh[d] * wk[(size_t)d * DD];
    ws[c * 2048 + h * 512 + tid] = acc;
}

// ---------- kB: streaming pass over x (proven R2/R4 hot loop) ----------
__global__ __launch_bounds__(512) void kB(const float* __restrict__ x,
                                          const float* __restrict__ g1,
                                          float* __restrict__ ws) {
    __shared__ float lds[16384];  // 64 KB
    int tid = threadIdx.x, lane = tid & 63, w = tid >> 6;
    const float4* p4 = (const float4*)ws;
    const float4* g4 = (const float4*)g1;
    const float scale = 0.088388347648318447f;  // 1/sqrt(128)
    float4 ga = g4[lane], gb = g4[64 + lane];
    float4 qa[4], qb[4];
    float qs[4];
#pragma unroll
    for (int h = 0; h < 4; ++h) {
        float4 sa = make_float4(0.f, 0.f, 0.f, 0.f), sb = sa;
#pragma unroll
        for (int c = 0; c < 8; ++c) {
            sa = f4add(sa, p4[c * 512 + h * 128 + lane]);
            sb = f4add(sb, p4[c * 512 + h * 128 + 64 + lane]);
        }
        qa[h] = f4muls(sa, ga, scale);
        qb[h] = f4muls(sb, gb, scale);
        qs[h] = wred(hsum4(qa[h]) + hsum4(qb[h]));
    }
    float sm[4], w2a[4];
    float4 Wa[4], Wb[4];
#pragma unroll
    for (int h = 0; h < 4; ++h) {
        sm[h] = 0.f; w2a[h] = 0.f;
        Wa[h] = make_float4(0.f, 0.f, 0.f, 0.f);
        Wb[h] = make_float4(0.f, 0.f, 0.f, 0.f);
    }
    size_t row0 = ((size_t)blockIdx.x * 8 + w) * 16;
    const float4* xb = (const float4*)x + row0 * 128;
    float4 nxa = xb[lane], nxc = xb[64 + lane];
    for (int r = 0; r < 16; ++r) {
        float4 xa = nxa, xc = nxc;
        if (r < 15) { nxa = xb[(r + 1) * 128 + lane]; nxc = xb[(r + 1) * 128 + 64 + lane]; }
        float ps = hsum4(xa) + hsum4(xc);
        float pss = dot4(xa, xa) + dot4(xc, xc);
        float p0 = dot4(xa, qa[0]) + dot4(xc, qb[0]);
        float p1 = dot4(xa, qa[1]) + dot4(xc, qb[1]);
        float p2 = dot4(xa, qa[2]) + dot4(xc, qb[2]);
        float p3 = dot4(xa, qa[3]) + dot4(xc, qb[3]);
        ps = wred(ps); pss = wred(pss);
        p0 = wred(p0); p1 = wred(p1); p2 = wred(p2); p3 = wred(p3);
        float m = ps * (1.f / 512.f);
        float rr = rsqrtf(pss * (1.f / 512.f) - m * m + 1e-5f);
        float rm = rr * m;
        float pd[4] = {p0, p1, p2, p3};
#pragma unroll
        for (int h = 0; h < 4; ++h) {
            float s = rr * pd[h] - rm * qs[h];   // O(1) scores: exp safe without shift
            float p = __expf(s);
            sm[h] += p;
            w2a[h] += p * rm;
            float pr = p * rr;
            Wa[h] = f4fma(Wa[h], pr, xa);
            Wb[h] = f4fma(Wb[h], pr, xc);
        }
    }
    int copy = blockIdx.x & 15;
    if (lane == 0) {
#pragma unroll
        for (int h = 0; h < 4; ++h) {
            lds[w * 4 + h] = sm[h];
            lds[32 + w * 4 + h] = w2a[h];
        }
    }
    __syncthreads();
    if (tid < 8) {
        int h = tid & 3;
        float a = 0.f;
        if (tid < 4) {
            for (int ww = 0; ww < 8; ++ww) a += lds[ww * 4 + h];
            atomicAdd(&ws[16384 + copy * 4 + h], a);
        } else {
            for (int ww = 0; ww < 8; ++ww) a += lds[32 + ww * 4 + h];
            atomicAdd(&ws[16448 + copy * 4 + h], a);
        }
    }
    __syncthreads();
    float4* lw4 = (float4*)(lds + w * 2048);
#pragma unroll
    for (int h = 0; h < 4; ++h) {
        lw4[h * 128 + lane] = Wa[h];
        lw4[h * 128 + 64 + lane] = Wb[h];
    }
    __syncthreads();
    float* cdst = ws + 16512 + (size_t)copy * 2048;
    for (int i = tid; i < 2048; i += 512) {
        float a = lds[i] + lds[2048 + i] + lds[4096 + i] + lds[6144 + i] +
                  lds[8192 + i] + lds[10240 + i] + lds[12288 + i] + lds[14336 + i];
        atomicAdd(cdst + i, a);
    }
}

// ---------- kD: fused epilogue, REGULAR launch, manual grid barriers ----------
// 128 blocks x 256 threads, zero LDS, low VGPR -> all blocks co-resident.
__global__ __launch_bounds__(256) void kD(const float* __restrict__ x,
                                          const float* __restrict__ w_in,
                                          const float* __restrict__ b_in,
                                          const float* __restrict__ w_out,
                                          const float* __restrict__ b_out,
                                          const float* __restrict__ w1,
                                          const float* __restrict__ b1,
                                          const float* __restrict__ w2,
                                          const float* __restrict__ b2,
                                          const float* __restrict__ g1,
                                          const float* __restrict__ be1,
                                          const float* __restrict__ g2,
                                          const float* __restrict__ be2,
                                          float* __restrict__ ws,
                                          float* __restrict__ out) {
    int tid = threadIdx.x, lane = tid & 63, w = tid >> 6;
    int j = blockIdx.x * 4 + w;
    int* bar = (int*)(ws + 50816);

    // ---- Phase 1: o[j] = Wv[j] . c(h) + bv[j]; reduce 16 contention copies ----
    {
        int h = j >> 7;  // uniform per block
        float smg = 0.f, w2g = 0.f;
#pragma unroll
        for (int c = 0; c < 16; ++c) {
            smg += ws[16384 + c * 4 + h];
            w2g += ws[16448 + c * 4 + h];
        }
        float inv = 1.f / smg, w2t = w2g * inv;
        float4 cra = make_float4(0.f, 0.f, 0.f, 0.f), crb = cra;
#pragma unroll
        for (int c = 0; c < 16; ++c) {
            const float4* cr = (const float4*)(ws + 16512 + c * 2048 + h * 512);
            cra = f4add(cra, cr[lane]);
            crb = f4add(crb, cr[64 + lane]);
        }
        const float4* g14 = (const float4*)g1;
        const float4* be14 = (const float4*)be1;
        float4 ca = caff4(cra, inv, w2t, g14[lane], be14[lane]);
        float4 cb = caff4(crb, inv, w2t, g14[64 + lane], be14[64 + lane]);
        const float4* wr = (const float4*)(w_in + (size_t)(2 * DD + j) * DD);
        float acc = wred(dot4(wr[lane], ca) + dot4(wr[64 + lane], cb));
        if (lane == 0) ws[49280 + j] = acc + b_in[2 * DD + j];
    }
    gbar(bar + 0, 128);

    // ---- Phase 2: y[j] = x0[j] + w_out[j].o + b_out[j] ----
    {
        const float4* wr = (const float4*)(w_out + (size_t)j * DD);
        const float4* o4 = (const float4*)(ws + 49280);
        float acc = wred(dot4(wr[lane], o4[lane]) + dot4(wr[64 + lane], o4[64 + lane]));
        if (lane == 0) ws[49792 + j] = x[j] + acc + b_out[j];
    }
    gbar(bar + 1, 128);

    // ---- Phase 3: h1[j] = relu(w1[j].LN(y) + b1[j]) ----
    {
        const float4* y4 = (const float4*)(ws + 49792);
        float4 ya = y4[lane], yb = y4[64 + lane];
        float ps = wred(hsum4(ya) + hsum4(yb));
        float pss = wred(dot4(ya, ya) + dot4(yb, yb));
        float m2 = ps * (1.f / 512.f);
        float r2 = rsqrtf(pss * (1.f / 512.f) - m2 * m2 + 1e-5f);
        const float4* g4 = (const float4*)g2;
        const float4* b4 = (const float4*)be2;
        float4 yna = lnrm4(ya, m2, r2, g4[lane], b4[lane]);
        float4 ynb = lnrm4(yb, m2, r2, g4[64 + lane], b4[64 + lane]);
        const float4* wr = (const float4*)(w1 + (size_t)j * DD);
        float acc = wred(dot4(wr[lane], yna) + dot4(wr[64 + lane], ynb));
        if (lane == 0) ws[50304 + j] = fmaxf(acc + b1[j], 0.f);
    }
    gbar(bar + 2, 128);

    // ---- Phase 4: out[j] = y[j] + w2[j].h1 + b2[j] ----
    {
        const float4* h4 = (const float4*)(ws + 50304);
        const float4* wr = (const float4*)(w2 + (size_t)j * DD);
        float acc = wred(dot4(wr[lane], h4[lane]) + dot4(wr[64 + lane], h4[64 + lane]));
        if (lane == 0) out[j] = ws[49792 + j] + acc + b2[j];
    }
}

extern "C" void kernel_launch(void* const* d_in, const int* in_sizes, int n_in,
                              void* d_out, int out_size, void* d_ws, size_t ws_size,
                              hipStream_t stream) {
    (void)in_sizes; (void)n_in; (void)out_size; (void)ws_size;
    const float* x = (const float*)d_in[0];
    const float* w_in = (const float*)d_in[1];
    const float* b_in = (const float*)d_in[2];
    const float* w_out = (const float*)d_in[3];
    const float* b_out = (const float*)d_in[4];
    const float* w1 = (const float*)d_in[5];
    const float* b1 = (const float*)d_in[6];
    const float* w2 = (const float*)d_in[7];
    const float* b2 = (const float*)d_in[8];
    const float* g1 = (const float*)d_in[9];
    const float* be1 = (const float*)d_in[10];
    const float* g2 = (const float*)d_in[11];
    const float* be2 = (const float*)d_in[12];
    float* ws = (float*)d_ws;
    float* out = (float*)d_out;

    hipLaunchKernelGGL(kA, dim3(32), dim3(512), 0, stream, x, w_in, b_in, g1, be1, ws);
    hipLaunchKernelGGL(kB, dim3(512), dim3(512), 0, stream, x, g1, ws);
    hipLaunchKernelGGL(kD, dim3(128), dim3(256), 0, stream,
                       x, w_in, b_in, w_out, b_out, w1, b1, w2, b2,
                       g1, be1, g2, be2, ws, out);
}

// Round 7
// 244.687 us; speedup vs baseline: 1.2456x; 1.0851x over previous
//
#include <hip/hip_runtime.h>
#include <math.h>

#define DD 512

// ---------- workspace layout (float offsets) ----------
// 0     : p[8][4][512]     qk partials: [chunk c][head h][col e], raw
// 16384 : sm_c[16][4]      16 contention copies of softmax denom per head
// 16448 : w2_c[16][4]      16 copies of weighted-rm sums
// 16512 : c_raw[16][2048]  16 contention copies of weighted-x context (atomics)
// 49280 : o[512]           attention output
// 49792 : y[512]           residual row
// 50304 : h1[512]          MLP hidden

__device__ __forceinline__ float dot4(float4 a, float4 b) {
    return a.x * b.x + a.y * b.y + a.z * b.z + a.w * b.w;
}
__device__ __forceinline__ float wred(float v) {
#pragma unroll
    for (int m = 32; m; m >>= 1) v += __shfl_xor(v, m, 64);
    return v;
}
__device__ __forceinline__ float4 f4fma(float4 acc, float s, float4 v) {
    acc.x += s * v.x; acc.y += s * v.y; acc.z += s * v.z; acc.w += s * v.w;
    return acc;
}
__device__ __forceinline__ float4 f4add(float4 a, float4 b) {
    a.x += b.x; a.y += b.y; a.z += b.z; a.w += b.w; return a;
}
__device__ __forceinline__ float4 f4muls(float4 a, float4 g, float s) {
    a.x *= g.x * s; a.y *= g.y * s; a.z *= g.z * s; a.w *= g.w * s; return a;
}
__device__ __forceinline__ float hsum4(float4 a) { return a.x + a.y + a.z + a.w; }
__device__ __forceinline__ float4 lnrm4(float4 v, float m, float r, float4 g, float4 b) {
    float4 o;
    o.x = (v.x - m) * r * g.x + b.x; o.y = (v.y - m) * r * g.y + b.y;
    o.z = (v.z - m) * r * g.z + b.z; o.w = (v.w - m) * r * g.w + b.w;
    return o;
}
__device__ __forceinline__ float4 caff4(float4 c, float inv, float w2t, float4 g, float4 b) {
    float4 o;
    o.x = g.x * (c.x * inv - w2t) + b.x; o.y = g.y * (c.y * inv - w2t) + b.y;
    o.z = g.z * (c.z * inv - w2t) + b.z; o.w = g.w * (c.w * inv - w2t) + b.w;
    return o;
}

// ---------- kA: fused q + qk chunk partials (32 blocks: h = bi>>3, c = bi&7) ----------
// block bi: LN(x0); q[h*128 + c*16 .. +15]; p[c][h][e] = sum_{d in chunk} q_d * Wk[.,e]
// Also zero-inits the atomic accumulation buffers (ws poisoned 0xAA each call).
__global__ __launch_bounds__(512) void kA(const float* __restrict__ x,
                                          const float* __restrict__ w_in,
                                          const float* __restrict__ b_in,
                                          const float* __restrict__ g1,
                                          const float* __restrict__ be1,
                                          float* __restrict__ ws) {
    __shared__ float qh[16];
    int bi = blockIdx.x, tid = threadIdx.x, lane = tid & 63, w = tid >> 6;
    int h = bi >> 3, c = bi & 7;
    // zero-init: c_raw (32 blocks x 1024 floats) + stats
    ws[16512 + bi * 1024 + tid] = 0.f;
    ws[16512 + bi * 1024 + 512 + tid] = 0.f;
    if (bi == 0 && tid < 128) ws[16384 + tid] = 0.f;
    // LN(x0): every wave computes redundantly (2 KB read, L2-shared)
    const float4* x4 = (const float4*)x;
    float4 a = x4[lane], b = x4[64 + lane];
    float ps = wred(hsum4(a) + hsum4(b));
    float pss = wred(dot4(a, a) + dot4(b, b));
    float m = ps * (1.f / 512.f);
    float r = rsqrtf(pss * (1.f / 512.f) - m * m + 1e-5f);
    const float4* g4 = (const float4*)g1;
    const float4* bb4 = (const float4*)be1;
    float4 xna = lnrm4(a, m, r, g4[lane], bb4[lane]);
    float4 xnb = lnrm4(b, m, r, g4[64 + lane], bb4[64 + lane]);
    int j0 = h * 128 + c * 16;
    const float4* wr = (const float4*)(w_in + (size_t)(j0 + w * 2) * DD);
    for (int i = 0; i < 2; ++i) {
        float acc = wred(dot4(wr[i * 128 + lane], xna) + dot4(wr[i * 128 + 64 + lane], xnb));
        if (lane == 0) qh[w * 2 + i] = acc + b_in[j0 + w * 2 + i];
    }
    __syncthreads();
    const float* wk = w_in + (size_t)(DD + j0) * DD + tid;
    float acc = 0.f;
#pragma unroll
    for (int d = 0; d < 16; ++d) acc += qh[d] * wk[(size_t)d * DD];
    ws[c * 2048 + h * 512 + tid] = acc;
}

// ---------- kB: streaming pass over x; shift-free softmax; atomic context tail ----------
// 512 blocks x 512 threads, 16 rows/wave  (hot loop = proven R2/R4 version)
__global__ __launch_bounds__(512) void kB(const float* __restrict__ x,
                                          const float* __restrict__ g1,
                                          float* __restrict__ ws) {
    __shared__ float lds[16384];  // 64 KB
    int tid = threadIdx.x, lane = tid & 63, w = tid >> 6;
    const float4* p4 = (const float4*)ws;
    const float4* g4 = (const float4*)g1;
    const float scale = 0.088388347648318447f;  // 1/sqrt(128)
    float4 ga = g4[lane], gb = g4[64 + lane];
    float4 qa[4], qb[4];
    float qs[4];
#pragma unroll
    for (int h = 0; h < 4; ++h) {
        float4 sa = make_float4(0.f, 0.f, 0.f, 0.f), sb = sa;
#pragma unroll
        for (int c = 0; c < 8; ++c) {
            sa = f4add(sa, p4[c * 512 + h * 128 + lane]);
            sb = f4add(sb, p4[c * 512 + h * 128 + 64 + lane]);
        }
        qa[h] = f4muls(sa, ga, scale);
        qb[h] = f4muls(sb, gb, scale);
        qs[h] = wred(hsum4(qa[h]) + hsum4(qb[h]));
    }
    float sm[4], w2a[4];
    float4 Wa[4], Wb[4];
#pragma unroll
    for (int h = 0; h < 4; ++h) {
        sm[h] = 0.f; w2a[h] = 0.f;
        Wa[h] = make_float4(0.f, 0.f, 0.f, 0.f);
        Wb[h] = make_float4(0.f, 0.f, 0.f, 0.f);
    }
    size_t row0 = ((size_t)blockIdx.x * 8 + w) * 16;
    const float4* xb = (const float4*)x + row0 * 128;
    float4 nxa = xb[lane], nxc = xb[64 + lane];
    for (int r = 0; r < 16; ++r) {
        float4 xa = nxa, xc = nxc;
        if (r < 15) { nxa = xb[(r + 1) * 128 + lane]; nxc = xb[(r + 1) * 128 + 64 + lane]; }
        float ps = hsum4(xa) + hsum4(xc);
        float pss = dot4(xa, xa) + dot4(xc, xc);
        float p0 = dot4(xa, qa[0]) + dot4(xc, qb[0]);
        float p1 = dot4(xa, qa[1]) + dot4(xc, qb[1]);
        float p2 = dot4(xa, qa[2]) + dot4(xc, qb[2]);
        float p3 = dot4(xa, qa[3]) + dot4(xc, qb[3]);
        ps = wred(ps); pss = wred(pss);
        p0 = wred(p0); p1 = wred(p1); p2 = wred(p2); p3 = wred(p3);
        float m = ps * (1.f / 512.f);
        float rr = rsqrtf(pss * (1.f / 512.f) - m * m + 1e-5f);
        float rm = rr * m;
        float pd[4] = {p0, p1, p2, p3};
#pragma unroll
        for (int h = 0; h < 4; ++h) {
            float s = rr * pd[h] - rm * qs[h];   // O(1) scores: exp safe without shift
            float p = __expf(s);
            sm[h] += p;
            w2a[h] += p * rm;
            float pr = p * rr;
            Wa[h] = f4fma(Wa[h], pr, xa);
            Wb[h] = f4fma(Wb[h], pr, xc);
        }
    }
    // ---- per-block stats combine (pure sums) + atomics into 16 contention copies ----
    int copy = blockIdx.x & 15;
    if (lane == 0) {
#pragma unroll
        for (int h = 0; h < 4; ++h) {
            lds[w * 4 + h] = sm[h];
            lds[32 + w * 4 + h] = w2a[h];
        }
    }
    __syncthreads();
    if (tid < 8) {
        int h = tid & 3;
        float a = 0.f;
        if (tid < 4) {
            for (int ww = 0; ww < 8; ++ww) a += lds[ww * 4 + h];
            atomicAdd(&ws[16384 + copy * 4 + h], a);
        } else {
            for (int ww = 0; ww < 8; ++ww) a += lds[32 + ww * 4 + h];
            atomicAdd(&ws[16448 + copy * 4 + h], a);
        }
    }
    __syncthreads();  // stats region consumed; reuse lds front for context reduce
    float4* lw4 = (float4*)(lds + w * 2048);
#pragma unroll
    for (int h = 0; h < 4; ++h) {
        lw4[h * 128 + lane] = Wa[h];
        lw4[h * 128 + 64 + lane] = Wb[h];
    }
    __syncthreads();
    // vectorized 8-slab reduce: thread handles 4 consecutive floats (b128 LDS reads)
    {
        float* cdst = ws + 16512 + (size_t)copy * 2048;
        const float4* l4 = (const float4*)lds;
        int i = tid;  // float4 index, 512 threads cover 2048 floats
        float4 a = f4add(f4add(f4add(l4[i], l4[512 + i]), f4add(l4[1024 + i], l4[1536 + i])),
                         f4add(f4add(l4[2048 + i], l4[2560 + i]), f4add(l4[3072 + i], l4[3584 + i])));
        atomicAdd(cdst + i * 4 + 0, a.x);
        atomicAdd(cdst + i * 4 + 1, a.y);
        atomicAdd(cdst + i * 4 + 2, a.z);
        atomicAdd(cdst + i * 4 + 3, a.w);
    }
}

// ---------- kD1: o[j] = Wv[j] . c(h) + bv[j]; reduces 16 copies in-kernel ----------
__global__ __launch_bounds__(256) void kD1(const float* __restrict__ w_in,
                                           const float* __restrict__ b_in,
                                           const float* __restrict__ g1,
                                           const float* __restrict__ be1,
                                           float* __restrict__ ws) {
    int tid = threadIdx.x, lane = tid & 63, w = tid >> 6;
    int j = blockIdx.x * 4 + w;
    int h = j >> 7;  // uniform per block (4 consecutive j, 4|128)
    float smg = 0.f, w2g = 0.f;
#pragma unroll
    for (int c = 0; c < 16; ++c) {
        smg += ws[16384 + c * 4 + h];
        w2g += ws[16448 + c * 4 + h];
    }
    float inv = 1.f / smg, w2t = w2g * inv;
    float4 cra = make_float4(0.f, 0.f, 0.f, 0.f), crb = cra;
#pragma unroll
    for (int c = 0; c < 16; ++c) {
        const float4* cr = (const float4*)(ws + 16512 + c * 2048 + h * 512);
        cra = f4add(cra, cr[lane]);
        crb = f4add(crb, cr[64 + lane]);
    }
    const float4* g14 = (const float4*)g1;
    const float4* be14 = (const float4*)be1;
    float4 ca = caff4(cra, inv, w2t, g14[lane], be14[lane]);
    float4 cb = caff4(crb, inv, w2t, g14[64 + lane], be14[64 + lane]);
    const float4* wr = (const float4*)(w_in + (size_t)(2 * DD + j) * DD);
    float acc = wred(dot4(wr[lane], ca) + dot4(wr[64 + lane], cb));
    if (lane == 0) ws[49280 + j] = acc + b_in[2 * DD + j];
}

// ---------- kD2: y[i] = x0[i] + dot(w_out[i], o) + b_out[i] ----------
__global__ __launch_bounds__(256) void kD2(const float* __restrict__ x,
                                           const float* __restrict__ w_out,
                                           const float* __restrict__ b_out,
                                           float* __restrict__ ws) {
    int lane = threadIdx.x & 63;
    int j = blockIdx.x * 4 + (threadIdx.x >> 6);
    const float4* wr = (const float4*)(w_out + (size_t)j * DD);
    const float4* o4 = (const float4*)(ws + 49280);
    float acc = wred(dot4(wr[lane], o4[lane]) + dot4(wr[64 + lane], o4[64 + lane]));
    if (lane == 0) ws[49792 + j] = x[j] + acc + b_out[j];
}

// ---------- kD3: h1[j] = relu(dot(w1[j], LN(y)) + b1[j]); LN2 stats per-wave ----------
__global__ __launch_bounds__(256) void kD3(const float* __restrict__ w1,
                                           const float* __restrict__ b1,
                                           const float* __restrict__ g2,
                                           const float* __restrict__ be2,
                                           float* __restrict__ ws) {
    int lane = threadIdx.x & 63;
    int j = blockIdx.x * 4 + (threadIdx.x >> 6);
    const float4* y4 = (const float4*)(ws + 49792);
    float4 ya = y4[lane], yb = y4[64 + lane];
    float ps = wred(hsum4(ya) + hsum4(yb));
    float pss = wred(dot4(ya, ya) + dot4(yb, yb));
    float m2 = ps * (1.f / 512.f);
    float r2 = rsqrtf(pss * (1.f / 512.f) - m2 * m2 + 1e-5f);
    const float4* g4 = (const float4*)g2;
    const float4* b4 = (const float4*)be2;
    float4 yna = lnrm4(ya, m2, r2, g4[lane], b4[lane]);
    float4 ynb = lnrm4(yb, m2, r2, g4[64 + lane], b4[64 + lane]);
    const float4* wr = (const float4*)(w1 + (size_t)j * DD);
    float acc = wred(dot4(wr[lane], yna) + dot4(wr[64 + lane], ynb));
    if (lane == 0) ws[50304 + j] = fmaxf(acc + b1[j], 0.f);
}

// ---------- kD4: out[j] = y[j] + dot(w2[j], h1) + b2[j] ----------
__global__ __launch_bounds__(256) void kD4(const float* __restrict__ w2,
                                           const float* __restrict__ b2,
                                           const float* __restrict__ ws,
                                           float* __restrict__ out) {
    int lane = threadIdx.x & 63;
    int j = blockIdx.x * 4 + (threadIdx.x >> 6);
    const float4* h4 = (const float4*)(ws + 50304);
    const float4* wr = (const float4*)(w2 + (size_t)j * DD);
    float acc = wred(dot4(wr[lane], h4[lane]) + dot4(wr[64 + lane], h4[64 + lane]));
    if (lane == 0) out[j] = ws[49792 + j] + acc + b2[j];
}

extern "C" void kernel_launch(void* const* d_in, const int* in_sizes, int n_in,
                              void* d_out, int out_size, void* d_ws, size_t ws_size,
                              hipStream_t stream) {
    (void)in_sizes; (void)n_in; (void)out_size; (void)ws_size;
    const float* x = (const float*)d_in[0];
    const float* w_in = (const float*)d_in[1];
    const float* b_in = (const float*)d_in[2];
    const float* w_out = (const float*)d_in[3];
    const float* b_out = (const float*)d_in[4];
    const float* w1 = (const float*)d_in[5];
    const float* b1 = (const float*)d_in[6];
    const float* w2 = (const float*)d_in[7];
    const float* b2 = (const float*)d_in[8];
    const float* g1 = (const float*)d_in[9];
    const float* be1 = (const float*)d_in[10];
    const float* g2 = (const float*)d_in[11];
    const float* be2 = (const float*)d_in[12];
    float* ws = (float*)d_ws;
    float* out = (float*)d_out;

    hipLaunchKernelGGL(kA, dim3(32), dim3(512), 0, stream, x, w_in, b_in, g1, be1, ws);
    hipLaunchKernelGGL(kB, dim3(512), dim3(512), 0, stream, x, g1, ws);
    hipLaunchKernelGGL(kD1, dim3(128), dim3(256), 0, stream, w_in, b_in, g1, be1, ws);
    hipLaunchKernelGGL(kD2, dim3(128), dim3(256), 0, stream, x, w_out, b_out, ws);
    hipLaunchKernelGGL(kD3, dim3(128), dim3(256), 0, stream, w1, b1, g2, be2, ws);
    hipLaunchKernelGGL(kD4, dim3(128), dim3(256), 0, stream, w2, b2, ws, out);
}

// Round 8
// 235.872 us; speedup vs baseline: 1.2921x; 1.0374x over previous
//
#include <hip/hip_runtime.h>
#include <math.h>

#define DD 512

// ---------- workspace layout (float offsets) ----------
// 0     : p[4][4][512]     qk partials: [chunk c][head h][col e], raw
// 8192  : sm_c[16][4]      16 contention copies of softmax denom per head
// 8256  : w2_c[16][4]      16 copies of weighted-rm sums
// 8448  : c_raw[16][2048]  16 contention copies of weighted-x context (atomics)
// 41216 : o[512]           attention output
// 41728 : y[512]           residual row
// 42240 : h1[512]          MLP hidden

__device__ __forceinline__ float dot4(float4 a, float4 b) {
    return a.x * b.x + a.y * b.y + a.z * b.z + a.w * b.w;
}
__device__ __forceinline__ float wred(float v) {
#pragma unroll
    for (int m = 32; m; m >>= 1) v += __shfl_xor(v, m, 64);
    return v;
}
__device__ __forceinline__ float4 f4fma(float4 acc, float s, float4 v) {
    acc.x += s * v.x; acc.y += s * v.y; acc.z += s * v.z; acc.w += s * v.w;
    return acc;
}
__device__ __forceinline__ float4 f4add(float4 a, float4 b) {
    a.x += b.x; a.y += b.y; a.z += b.z; a.w += b.w; return a;
}
__device__ __forceinline__ float4 f4muls(float4 a, float4 g, float s) {
    a.x *= g.x * s; a.y *= g.y * s; a.z *= g.z * s; a.w *= g.w * s; return a;
}
__device__ __forceinline__ float hsum4(float4 a) { return a.x + a.y + a.z + a.w; }
__device__ __forceinline__ float4 lnrm4(float4 v, float m, float r, float4 g, float4 b) {
    float4 o;
    o.x = (v.x - m) * r * g.x + b.x; o.y = (v.y - m) * r * g.y + b.y;
    o.z = (v.z - m) * r * g.z + b.z; o.w = (v.w - m) * r * g.w + b.w;
    return o;
}
__device__ __forceinline__ float4 caff4(float4 c, float inv, float w2t, float4 g, float4 b) {
    float4 o;
    o.x = g.x * (c.x * inv - w2t) + b.x; o.y = g.y * (c.y * inv - w2t) + b.y;
    o.z = g.z * (c.z * inv - w2t) + b.z; o.w = g.w * (c.w * inv - w2t) + b.w;
    return o;
}

// ---------- kA: fused q + qk chunk partials (16 blocks: h = bi>>2, c = bi&3) ----------
// block bi: LN(x0); q[h*128 + c*32 .. +31]; p[c][h][e] = sum_{d in chunk} q_d * Wk[.,e]
// Also zero-inits the atomic accumulation buffers (ws poisoned 0xAA every call).
__global__ __launch_bounds__(512) void kA(const float* __restrict__ x,
                                          const float* __restrict__ w_in,
                                          const float* __restrict__ b_in,
                                          const float* __restrict__ g1,
                                          const float* __restrict__ be1,
                                          float* __restrict__ ws) {
    __shared__ float qh[32];
    int bi = blockIdx.x, tid = threadIdx.x, lane = tid & 63, w = tid >> 6;
    int h = bi >> 2, c = bi & 3;
    // zero-init: c_raw (16 blocks x 512 thr x 4 floats = 32768) + stats
    {
        float4 z = make_float4(0.f, 0.f, 0.f, 0.f);
        ((float4*)(ws + 8448))[bi * 512 + tid] = z;
        if (bi == 0 && tid < 128) ws[8192 + tid] = 0.f;
    }
    // LN(x0): every wave computes redundantly (2 KB read)
    const float4* x4 = (const float4*)x;
    float4 a = x4[lane], b = x4[64 + lane];
    float ps = wred(hsum4(a) + hsum4(b));
    float pss = wred(dot4(a, a) + dot4(b, b));
    float m = ps * (1.f / 512.f);
    float r = rsqrtf(pss * (1.f / 512.f) - m * m + 1e-5f);
    const float4* g4 = (const float4*)g1;
    const float4* bb4 = (const float4*)be1;
    float4 xna = lnrm4(a, m, r, g4[lane], bb4[lane]);
    float4 xnb = lnrm4(b, m, r, g4[64 + lane], bb4[64 + lane]);
    // q chunk: wave w computes rows j0+w*4 .. +3
    int j0 = h * 128 + c * 32;
    const float4* wr = (const float4*)(w_in + (size_t)(j0 + w * 4) * DD);
    for (int i = 0; i < 4; ++i) {
        float acc = wred(dot4(wr[i * 128 + lane], xna) + dot4(wr[i * 128 + 64 + lane], xnb));
        if (lane == 0) qh[w * 4 + i] = acc + b_in[j0 + w * 4 + i];
    }
    __syncthreads();
    // chunk partial over e = tid (coalesced)
    const float* wk = w_in + (size_t)(DD + j0) * DD + tid;
    float acc = 0.f;
#pragma unroll
    for (int d = 0; d < 32; ++d) acc += qh[d] * wk[(size_t)d * DD];
    ws[c * 2048 + h * 512 + tid] = acc;
}

// ---------- kB: streaming pass over x; shift-free softmax; atomic context tail ----------
// 512 blocks x 512 threads, 16 rows/wave
__global__ __launch_bounds__(512) void kB(const float* __restrict__ x,
                                          const float* __restrict__ g1,
                                          float* __restrict__ ws) {
    __shared__ float lds[16384];  // 64 KB
    int tid = threadIdx.x, lane = tid & 63, w = tid >> 6;
    const float4* p4 = (const float4*)ws;
    const float4* g4 = (const float4*)g1;
    const float scale = 0.088388347648318447f;  // 1/sqrt(128)
    float4 ga = g4[lane], gb = g4[64 + lane];
    float4 qa[4], qb[4];
    float qs[4];
#pragma unroll
    for (int h = 0; h < 4; ++h) {
        float4 sa = f4add(f4add(p4[h * 128 + lane], p4[512 + h * 128 + lane]),
                          f4add(p4[1024 + h * 128 + lane], p4[1536 + h * 128 + lane]));
        float4 sb = f4add(f4add(p4[h * 128 + 64 + lane], p4[512 + h * 128 + 64 + lane]),
                          f4add(p4[1024 + h * 128 + 64 + lane], p4[1536 + h * 128 + 64 + lane]));
        qa[h] = f4muls(sa, ga, scale);
        qb[h] = f4muls(sb, gb, scale);
        qs[h] = wred(hsum4(qa[h]) + hsum4(qb[h]));
    }
    float sm[4], w2a[4];
    float4 Wa[4], Wb[4];
#pragma unroll
    for (int h = 0; h < 4; ++h) {
        sm[h] = 0.f; w2a[h] = 0.f;
        Wa[h] = make_float4(0.f, 0.f, 0.f, 0.f);
        Wb[h] = make_float4(0.f, 0.f, 0.f, 0.f);
    }
    size_t row0 = ((size_t)blockIdx.x * 8 + w) * 16;
    const float4* xb = (const float4*)x + row0 * 128;
    float4 nxa = xb[lane], nxc = xb[64 + lane];
    for (int r = 0; r < 16; ++r) {
        float4 xa = nxa, xc = nxc;
        if (r < 15) { nxa = xb[(r + 1) * 128 + lane]; nxc = xb[(r + 1) * 128 + 64 + lane]; }
        float ps = hsum4(xa) + hsum4(xc);
        float pss = dot4(xa, xa) + dot4(xc, xc);
        float p0 = dot4(xa, qa[0]) + dot4(xc, qb[0]);
        float p1 = dot4(xa, qa[1]) + dot4(xc, qb[1]);
        float p2 = dot4(xa, qa[2]) + dot4(xc, qb[2]);
        float p3 = dot4(xa, qa[3]) + dot4(xc, qb[3]);
        ps = wred(ps); pss = wred(pss);
        p0 = wred(p0); p1 = wred(p1); p2 = wred(p2); p3 = wred(p3);
        float m = ps * (1.f / 512.f);
        float rr = rsqrtf(pss * (1.f / 512.f) - m * m + 1e-5f);
        float rm = rr * m;
        float pd[4] = {p0, p1, p2, p3};
#pragma unroll
        for (int h = 0; h < 4; ++h) {
            float s = rr * pd[h] - rm * qs[h];   // O(1) scores: exp safe without shift
            float p = __expf(s);
            sm[h] += p;
            w2a[h] += p * rm;
            float pr = p * rr;
            Wa[h] = f4fma(Wa[h], pr, xa);
            Wb[h] = f4fma(Wb[h], pr, xc);
        }
    }
    // ---- per-block stats combine (pure sums) + atomics into 16 contention copies ----
    int copy = blockIdx.x & 15;
    if (lane == 0) {
#pragma unroll
        for (int h = 0; h < 4; ++h) {
            lds[w * 4 + h] = sm[h];
            lds[32 + w * 4 + h] = w2a[h];
        }
    }
    __syncthreads();
    if (tid < 8) {
        int h = tid & 3;
        float a = 0.f;
        if (tid < 4) {
            for (int ww = 0; ww < 8; ++ww) a += lds[ww * 4 + h];
            atomicAdd(&ws[8192 + copy * 4 + h], a);
        } else {
            for (int ww = 0; ww < 8; ++ww) a += lds[32 + ww * 4 + h];
            atomicAdd(&ws[8256 + copy * 4 + h], a);
        }
    }
    __syncthreads();  // stats region consumed; reuse lds front for context reduce
    float4* lw4 = (float4*)(lds + w * 2048);
#pragma unroll
    for (int h = 0; h < 4; ++h) {
        lw4[h * 128 + lane] = Wa[h];
        lw4[h * 128 + 64 + lane] = Wb[h];
    }
    __syncthreads();
    float* cdst = ws + 8448 + (size_t)copy * 2048;
    for (int i = tid; i < 2048; i += 512) {
        float a = lds[i] + lds[2048 + i] + lds[4096 + i] + lds[6144 + i] +
                  lds[8192 + i] + lds[10240 + i] + lds[12288 + i] + lds[14336 + i];
        atomicAdd(cdst + i, a);
    }
}

// ---------- kD1: o[j] = Wv[j] . c(h) + bv[j]; reduces 16 copies in-kernel ----------
__global__ __launch_bounds__(256) void kD1(const float* __restrict__ w_in,
                                           const float* __restrict__ b_in,
                                           const float* __restrict__ g1,
                                           const float* __restrict__ be1,
                                           float* __restrict__ ws) {
    int tid = threadIdx.x, lane = tid & 63, w = tid >> 6;
    int j = blockIdx.x * 4 + w;
    int h = j >> 7;  // uniform per block (4 consecutive j, 4|128)
    float smg = 0.f, w2g = 0.f;
#pragma unroll
    for (int c = 0; c < 16; ++c) {
        smg += ws[8192 + c * 4 + h];
        w2g += ws[8256 + c * 4 + h];
    }
    float inv = 1.f / smg, w2t = w2g * inv;
    float4 cra = make_float4(0.f, 0.f, 0.f, 0.f), crb = cra;
#pragma unroll
    for (int c = 0; c < 16; ++c) {
        const float4* cr = (const float4*)(ws + 8448 + c * 2048 + h * 512);
        cra = f4add(cra, cr[lane]);
        crb = f4add(crb, cr[64 + lane]);
    }
    const float4* g14 = (const float4*)g1;
    const float4* be14 = (const float4*)be1;
    float4 ca = caff4(cra, inv, w2t, g14[lane], be14[lane]);
    float4 cb = caff4(crb, inv, w2t, g14[64 + lane], be14[64 + lane]);
    const float4* wr = (const float4*)(w_in + (size_t)(2 * DD + j) * DD);
    float acc = wred(dot4(wr[lane], ca) + dot4(wr[64 + lane], cb));
    if (lane == 0) ws[41216 + j] = acc + b_in[2 * DD + j];
}

// ---------- kD2: y[i] = x0[i] + dot(w_out[i], o) + b_out[i] ----------
__global__ __launch_bounds__(256) void kD2(const float* __restrict__ x,
                                           const float* __restrict__ w_out,
                                           const float* __restrict__ b_out,
                                           float* __restrict__ ws) {
    int lane = threadIdx.x & 63;
    int j = blockIdx.x * 4 + (threadIdx.x >> 6);
    const float4* wr = (const float4*)(w_out + (size_t)j * DD);
    const float4* o4 = (const float4*)(ws + 41216);
    float acc = wred(dot4(wr[lane], o4[lane]) + dot4(wr[64 + lane], o4[64 + lane]));
    if (lane == 0) ws[41728 + j] = x[j] + acc + b_out[j];
}

// ---------- kD3: h1[j] = relu(dot(w1[j], LN(y)) + b1[j]); LN2 stats per-wave ----------
__global__ __launch_bounds__(256) void kD3(const float* __restrict__ w1,
                                           const float* __restrict__ b1,
                                           const float* __restrict__ g2,
                                           const float* __restrict__ be2,
                                           float* __restrict__ ws) {
    int lane = threadIdx.x & 63;
    int j = blockIdx.x * 4 + (threadIdx.x >> 6);
    const float4* y4 = (const float4*)(ws + 41728);
    float4 ya = y4[lane], yb = y4[64 + lane];
    float ps = wred(hsum4(ya) + hsum4(yb));
    float pss = wred(dot4(ya, ya) + dot4(yb, yb));
    float m2 = ps * (1.f / 512.f);
    float r2 = rsqrtf(pss * (1.f / 512.f) - m2 * m2 + 1e-5f);
    const float4* g4 = (const float4*)g2;
    const float4* b4 = (const float4*)be2;
    float4 yna = lnrm4(ya, m2, r2, g4[lane], b4[lane]);
    float4 ynb = lnrm4(yb, m2, r2, g4[64 + lane], b4[64 + lane]);
    const float4* wr = (const float4*)(w1 + (size_t)j * DD);
    float acc = wred(dot4(wr[lane], yna) + dot4(wr[64 + lane], ynb));
    if (lane == 0) ws[42240 + j] = fmaxf(acc + b1[j], 0.f);
}

// ---------- kD4: out[j] = y[j] + dot(w2[j], h1) + b2[j] ----------
__global__ __launch_bounds__(256) void kD4(const float* __restrict__ w2,
                                           const float* __restrict__ b2,
                                           const float* __restrict__ ws,
                                           float* __restrict__ out) {
    int lane = threadIdx.x & 63;
    int j = blockIdx.x * 4 + (threadIdx.x >> 6);
    const float4* h4 = (const float4*)(ws + 42240);
    const float4* wr = (const float4*)(w2 + (size_t)j * DD);
    float acc = wred(dot4(wr[lane], h4[lane]) + dot4(wr[64 + lane], h4[64 + lane]));
    if (lane == 0) out[j] = ws[41728 + j] + acc + b2[j];
}

extern "C" void kernel_launch(void* const* d_in, const int* in_sizes, int n_in,
                              void* d_out, int out_size, void* d_ws, size_t ws_size,
                              hipStream_t stream) {
    (void)in_sizes; (void)n_in; (void)out_size; (void)ws_size;
    const float* x = (const float*)d_in[0];
    const float* w_in = (const float*)d_in[1];
    const float* b_in = (const float*)d_in[2];
    const float* w_out = (const float*)d_in[3];
    const float* b_out = (const float*)d_in[4];
    const float* w1 = (const float*)d_in[5];
    const float* b1 = (const float*)d_in[6];
    const float* w2 = (const float*)d_in[7];
    const float* b2 = (const float*)d_in[8];
    const float* g1 = (const float*)d_in[9];
    const float* be1 = (const float*)d_in[10];
    const float* g2 = (const float*)d_in[11];
    const float* be2 = (const float*)d_in[12];
    float* ws = (float*)d_ws;
    float* out = (float*)d_out;

    hipLaunchKernelGGL(kA, dim3(16), dim3(512), 0, stream, x, w_in, b_in, g1, be1, ws);
    hipLaunchKernelGGL(kB, dim3(512), dim3(512), 0, stream, x, g1, ws);
    hipLaunchKernelGGL(kD1, dim3(128), dim3(256), 0, stream, w_in, b_in, g1, be1, ws);
    hipLaunchKernelGGL(kD2, dim3(128), dim3(256), 0, stream, x, w_out, b_out, ws);
    hipLaunchKernelGGL(kD3, dim3(128), dim3(256), 0, stream, w1, b1, g2, be2, ws);
    hipLaunchKernelGGL(kD4, dim3(128), dim3(256), 0, stream, w2, b2, ws, out);
}